// Round 1
// baseline (578.662 us; speedup 1.0000x reference)
//
#include <hip/hip_runtime.h>

typedef unsigned int u32;
typedef unsigned long long u64;

// Problem constants
#define T_ 4
#define B_ 16
#define N_ 256
#define C_ 256
#define H_ 8
#define D_ 32
#define BNC_ 1048576   // B*N*C
#define NELEM 4194304  // T*B*N*C

// ---------------------------------------------------------------------------
// GEMM + eval-BatchNorm epilogue.
// Out[m, o] = BN(sum_c A[m, c] * W[o, c])   A:[16384,256] W:[256,256] row-major
// 64x64 tile, BK=32, k-major LDS (transposed on store), 4x4 microtile.
// ---------------------------------------------------------------------------
__global__ __launch_bounds__(256) void gemm_bn(
    const float* __restrict__ A, const float* __restrict__ W,
    const float* __restrict__ bnp, float* __restrict__ Out)
{
  __shared__ float As[32][68];
  __shared__ float Ws[32][68];
  const int tid = threadIdx.x;
  const int m0 = blockIdx.y << 6;
  const int n0 = blockIdx.x << 6;
  const int tx = tid & 15, ty = tid >> 4;
  const int lrow = tid >> 3;         // 0..31
  const int lk = (tid & 7) << 2;     // 0,4,...,28

  float acc[4][4] = {};

  for (int k0 = 0; k0 < 256; k0 += 32) {
    float4 a0 = *(const float4*)(A + (size_t)(m0 + lrow) * 256 + k0 + lk);
    float4 a1 = *(const float4*)(A + (size_t)(m0 + lrow + 32) * 256 + k0 + lk);
    float4 w0 = *(const float4*)(W + (size_t)(n0 + lrow) * 256 + k0 + lk);
    float4 w1 = *(const float4*)(W + (size_t)(n0 + lrow + 32) * 256 + k0 + lk);
    __syncthreads();
    As[lk+0][lrow] = a0.x; As[lk+1][lrow] = a0.y; As[lk+2][lrow] = a0.z; As[lk+3][lrow] = a0.w;
    As[lk+0][lrow+32] = a1.x; As[lk+1][lrow+32] = a1.y; As[lk+2][lrow+32] = a1.z; As[lk+3][lrow+32] = a1.w;
    Ws[lk+0][lrow] = w0.x; Ws[lk+1][lrow] = w0.y; Ws[lk+2][lrow] = w0.z; Ws[lk+3][lrow] = w0.w;
    Ws[lk+0][lrow+32] = w1.x; Ws[lk+1][lrow+32] = w1.y; Ws[lk+2][lrow+32] = w1.z; Ws[lk+3][lrow+32] = w1.w;
    __syncthreads();
#pragma unroll
    for (int kk = 0; kk < 32; ++kk) {
      float4 av = *(const float4*)&As[kk][ty << 2];
      float4 bv = *(const float4*)&Ws[kk][tx << 2];
      acc[0][0] = fmaf(av.x, bv.x, acc[0][0]);
      acc[0][1] = fmaf(av.x, bv.y, acc[0][1]);
      acc[0][2] = fmaf(av.x, bv.z, acc[0][2]);
      acc[0][3] = fmaf(av.x, bv.w, acc[0][3]);
      acc[1][0] = fmaf(av.y, bv.x, acc[1][0]);
      acc[1][1] = fmaf(av.y, bv.y, acc[1][1]);
      acc[1][2] = fmaf(av.y, bv.z, acc[1][2]);
      acc[1][3] = fmaf(av.y, bv.w, acc[1][3]);
      acc[2][0] = fmaf(av.z, bv.x, acc[2][0]);
      acc[2][1] = fmaf(av.z, bv.y, acc[2][1]);
      acc[2][2] = fmaf(av.z, bv.z, acc[2][2]);
      acc[2][3] = fmaf(av.z, bv.w, acc[2][3]);
      acc[3][0] = fmaf(av.w, bv.x, acc[3][0]);
      acc[3][1] = fmaf(av.w, bv.y, acc[3][1]);
      acc[3][2] = fmaf(av.w, bv.z, acc[3][2]);
      acc[3][3] = fmaf(av.w, bv.w, acc[3][3]);
    }
  }

  // BN(eval): y = ((h - mean) * (gamma * rsqrt(var+eps))) + beta
  // Same rounding sequence as the reference's elementwise ops (no fma folding).
  const float* gma = bnp;
  const float* bta = bnp + 256;
  const float* mea = bnp + 512;
  const float* vra = bnp + 768;
  float sc[4], me[4], be[4];
#pragma unroll
  for (int jj = 0; jj < 4; ++jj) {
    int o = n0 + (tx << 2) + jj;
    sc[jj] = __fmul_rn(gma[o], 1.0f / sqrtf(__fadd_rn(vra[o], 1e-5f)));
    me[jj] = mea[o];
    be[jj] = bta[o];
  }
#pragma unroll
  for (int ii = 0; ii < 4; ++ii) {
    int row = m0 + (ty << 2) + ii;
    float4 y;
    y.x = __fadd_rn(__fmul_rn(__fsub_rn(acc[ii][0], me[0]), sc[0]), be[0]);
    y.y = __fadd_rn(__fmul_rn(__fsub_rn(acc[ii][1], me[1]), sc[1]), be[1]);
    y.z = __fadd_rn(__fmul_rn(__fsub_rn(acc[ii][2], me[2]), sc[2]), be[2]);
    y.w = __fadd_rn(__fmul_rn(__fsub_rn(acc[ii][3], me[3]), sc[3]), be[3]);
    *(float4*)(Out + (size_t)row * 256 + n0 + (tx << 2)) = y;
  }
}

// ---------------------------------------------------------------------------
// LIF over T (TAU=2, hard reset) + pack spikes into per-head 32-bit masks.
// h: [T,B,N,C] fp32.  mask[t][b][h][n] bit d = spike(c = h*32+d).
// One block per (b,n); thread = channel c; ballot packs 64 lanes -> 2 heads.
// ---------------------------------------------------------------------------
__global__ __launch_bounds__(256) void lif_pack(
    const float* __restrict__ h, u32* __restrict__ mask)
{
  const int blk = blockIdx.x;          // b*256 + n
  const int b = blk >> 8, n = blk & 255;
  const int c = threadIdx.x;
  const int wave = c >> 6, lane = c & 63;
  const size_t idx = ((size_t)b * 256 + n) * 256 + c;
  float v = 0.0f;
#pragma unroll
  for (int t = 0; t < 4; ++t) {
    float xv = h[idx + (size_t)t * BNC_];
    v = __fadd_rn(v, __fmul_rn(__fsub_rn(xv, v), 0.5f));
    bool s = (v >= 1.0f);              // sign of fl(v-1) == (v>=1)
    u64 bal = __ballot(s);
    const int h0 = wave << 1;
    u32* mptr = mask + ((size_t)(t * 16 + b) * 8) * 256 + n;
    if (lane == 0)  mptr[(size_t)h0 * 256]       = (u32)bal;
    if (lane == 32) mptr[(size_t)(h0 + 1) * 256] = (u32)(bal >> 32);
    v = s ? 0.0f : v;
  }
}

// ---------------------------------------------------------------------------
// Fused attention: QK^T (popcount) + rel-bias + exact top-64 threshold + PV.
// One block per (t,b,h); 4 waves, each wave owns one row at a time.
// outPV: [T,B,H,N,D] fp32.
// ---------------------------------------------------------------------------
__global__ __launch_bounds__(256) void attn_topk_pv(
    const u32* __restrict__ qmask, const u32* __restrict__ kmask,
    const u32* __restrict__ vmask, const float* __restrict__ table,
    float* __restrict__ outPV)
{
  __shared__ __align__(16) u32 kms[256];
  __shared__ __align__(16) u32 vms[256];
  __shared__ __align__(16) float bias[511];
  __shared__ __align__(16) float arow[4][256];

  const int tbh = blockIdx.x;
  const int hh = tbh & 7;
  const int tid = threadIdx.x;

  kms[tid] = kmask[((size_t)tbh << 8) + tid];
  vms[tid] = vmask[((size_t)tbh << 8) + tid];
  bias[tid] = table[tid * 8 + hh];
  if (tid < 255) bias[256 + tid] = table[(256 + tid) * 8 + hh];
  __syncthreads();

  const int wave = tid >> 6, lane = tid & 63;
  const int d = lane & 31, half = lane >> 5;

  for (int i = wave; i < 256; i += 4) {
    const u32 qm = qmask[((size_t)tbh << 8) + i];
    float a[4];
    u32 u[4];
#pragma unroll
    for (int r = 0; r < 4; ++r) {
      const int j = lane + (r << 6);
      const int m = __popc(qm & kms[j]);
      float av = __fmul_rn((float)m, 0.0625f);     // * C^-0.5 = 1/16 (exact)
      av = __fadd_rn(av, bias[j - i + 255]);        // one rounded add, == ref
      a[r] = av;
      const u32 bb = __float_as_uint(av);
      u[r] = bb ^ ((u32)((int)bb >> 31) | 0x80000000u);  // order-preserving map
    }
    // MSB-greedy search for the exact 64th-largest value (ties kept like ref)
    u32 t = 0u;
#pragma unroll
    for (int bit = 31; bit >= 0; --bit) {
      const u32 cand = t | (1u << bit);
      const int cnt = __popcll(__ballot(u[0] >= cand)) +
                      __popcll(__ballot(u[1] >= cand)) +
                      __popcll(__ballot(u[2] >= cand)) +
                      __popcll(__ballot(u[3] >= cand));
      if (cnt >= 64) t = cand;
    }
#pragma unroll
    for (int r = 0; r < 4; ++r)
      arow[wave][lane + (r << 6)] = (u[r] >= t) ? a[r] : 0.0f;
    // cross-lane LDS visibility within the wave (DS ops are in-order per wave;
    // the waitcnt + memory clobber also pins compiler ordering)
    asm volatile("s_waitcnt lgkmcnt(0)" ::: "memory");

    // PV: lane (half,d) sums its half of j over v-spike bits
    float s = 0.0f;
#pragma unroll 8
    for (int jj = 0; jj < 32; ++jj) {
      const int j = (half << 7) + (jj << 2);
      float4 a4 = *(const float4*)&arow[wave][j];
      uint4 v4 = *(const uint4*)&vms[j];
      if ((v4.x >> d) & 1u) s += a4.x;
      if ((v4.y >> d) & 1u) s += a4.y;
      if ((v4.z >> d) & 1u) s += a4.z;
      if ((v4.w >> d) & 1u) s += a4.w;
    }
    s += __shfl_xor(s, 32, 64);
    if (half == 0)
      outPV[(((size_t)tbh << 8) + i) * 32 + d] = s;
  }
}

// ---------------------------------------------------------------------------
// attn_lif: LIF over T on PV output, with [T,B,H,N,D] -> [T,B,N,C] transpose.
// Emits fp32 spikes (0/1) for the proj GEMM.
// ---------------------------------------------------------------------------
__global__ __launch_bounds__(256) void attn_lif(
    const float* __restrict__ pv, float* __restrict__ sout)
{
  const int blk = blockIdx.x;          // b*256 + n
  const int b = blk >> 8, n = blk & 255;
  const int c = threadIdx.x;
  const int hh = c >> 5, d = c & 31;
  float v = 0.0f;
#pragma unroll
  for (int t = 0; t < 4; ++t) {
    float xv = pv[(((size_t)(t * 16 + b) * 8 + hh) << 13) + (n << 5) + d];
    v = __fadd_rn(v, __fmul_rn(__fsub_rn(xv, v), 0.5f));
    bool s = (v >= 1.0f);
    sout[(((size_t)(t * 16 + b) << 8) + n) * 256 + c] = s ? 1.0f : 0.0f;
    v = s ? 0.0f : v;
  }
}

// ---------------------------------------------------------------------------
// Final LIF: hproj [T,B,N,C] -> d_out spikes [T,B,N,C]
// ---------------------------------------------------------------------------
__global__ __launch_bounds__(256) void final_lif(
    const float* __restrict__ hp, float* __restrict__ out)
{
  const size_t base = (size_t)blockIdx.x * 256 + threadIdx.x;
  float v = 0.0f;
#pragma unroll
  for (int t = 0; t < 4; ++t) {
    float xv = hp[base + (size_t)t * BNC_];
    v = __fadd_rn(v, __fmul_rn(__fsub_rn(xv, v), 0.5f));
    bool s = (v >= 1.0f);
    out[base + (size_t)t * BNC_] = s ? 1.0f : 0.0f;
    v = s ? 0.0f : v;
  }
}

// ---------------------------------------------------------------------------
extern "C" void kernel_launch(void* const* d_in, const int* in_sizes, int n_in,
                              void* d_out, int out_size, void* d_ws, size_t ws_size,
                              hipStream_t stream) {
  const float* x       = (const float*)d_in[0];
  const float* wq      = (const float*)d_in[1];
  const float* wk      = (const float*)d_in[2];
  const float* wv      = (const float*)d_in[3];
  const float* bnq     = (const float*)d_in[4];
  const float* bnk     = (const float*)d_in[5];
  const float* bnv     = (const float*)d_in[6];
  const float* proj_w  = (const float*)d_in[7];
  const float* proj_bn = (const float*)d_in[8];
  const float* rtable  = (const float*)d_in[9];
  float* out = (float*)d_out;

  float* ws = (float*)d_ws;
  float* hq = ws;                  // NELEM floats
  float* hk = ws + (size_t)NELEM;
  float* hv = ws + (size_t)NELEM * 2;
  u32* mq = (u32*)(ws + (size_t)NELEM * 3);   // 131072 u32 each
  u32* mk = mq + 131072;
  u32* mv = mk + 131072;
  float* outPV = hq;   // reuse: hq dead after mask extraction
  float* sout  = hk;
  float* hproj = hv;

  dim3 ggrid(4, 256);
  gemm_bn<<<ggrid, 256, 0, stream>>>(x, wq, bnq, hq);
  gemm_bn<<<ggrid, 256, 0, stream>>>(x, wk, bnk, hk);
  gemm_bn<<<ggrid, 256, 0, stream>>>(x, wv, bnv, hv);

  lif_pack<<<4096, 256, 0, stream>>>(hq, mq);
  lif_pack<<<4096, 256, 0, stream>>>(hk, mk);
  lif_pack<<<4096, 256, 0, stream>>>(hv, mv);

  attn_topk_pv<<<512, 256, 0, stream>>>(mq, mk, mv, rtable, outPV);

  attn_lif<<<4096, 256, 0, stream>>>(outPV, sout);

  gemm_bn<<<ggrid, 256, 0, stream>>>(sout, proj_w, proj_bn, hproj);

  final_lif<<<4096, 256, 0, stream>>>(hproj, out);
}

// Round 2
// 378.750 us; speedup vs baseline: 1.5278x; 1.5278x over previous
//
#include <hip/hip_runtime.h>

typedef unsigned int u32;
typedef unsigned long long u64;

// Problem constants
#define T_ 4
#define B_ 16
#define N_ 256
#define C_ 256
#define H_ 8
#define D_ 32
#define BNC_ 1048576   // B*N*C
#define NELEM 4194304  // T*B*N*C

// ---------------------------------------------------------------------------
// GEMM + eval-BatchNorm epilogue.
// Out[m, o] = BN(sum_c A[m, c] * W[o, c])   A:[16384,256] W:[256,256] row-major
// 64x64 tile, BK=32, k-major LDS (transposed on store), 4x4 microtile.
// NOTE: FMA chain per output is strict k-ascending — spike-exactness depends
// on preserving this order in any future change.
// ---------------------------------------------------------------------------
__global__ __launch_bounds__(256) void gemm_bn(
    const float* __restrict__ A, const float* __restrict__ W,
    const float* __restrict__ bnp, float* __restrict__ Out)
{
  __shared__ float As[32][68];
  __shared__ float Ws[32][68];
  const int tid = threadIdx.x;
  const int m0 = blockIdx.y << 6;
  const int n0 = blockIdx.x << 6;
  const int tx = tid & 15, ty = tid >> 4;
  const int lrow = tid >> 3;         // 0..31
  const int lk = (tid & 7) << 2;     // 0,4,...,28

  float acc[4][4] = {};

  for (int k0 = 0; k0 < 256; k0 += 32) {
    float4 a0 = *(const float4*)(A + (size_t)(m0 + lrow) * 256 + k0 + lk);
    float4 a1 = *(const float4*)(A + (size_t)(m0 + lrow + 32) * 256 + k0 + lk);
    float4 w0 = *(const float4*)(W + (size_t)(n0 + lrow) * 256 + k0 + lk);
    float4 w1 = *(const float4*)(W + (size_t)(n0 + lrow + 32) * 256 + k0 + lk);
    __syncthreads();
    As[lk+0][lrow] = a0.x; As[lk+1][lrow] = a0.y; As[lk+2][lrow] = a0.z; As[lk+3][lrow] = a0.w;
    As[lk+0][lrow+32] = a1.x; As[lk+1][lrow+32] = a1.y; As[lk+2][lrow+32] = a1.z; As[lk+3][lrow+32] = a1.w;
    Ws[lk+0][lrow] = w0.x; Ws[lk+1][lrow] = w0.y; Ws[lk+2][lrow] = w0.z; Ws[lk+3][lrow] = w0.w;
    Ws[lk+0][lrow+32] = w1.x; Ws[lk+1][lrow+32] = w1.y; Ws[lk+2][lrow+32] = w1.z; Ws[lk+3][lrow+32] = w1.w;
    __syncthreads();
#pragma unroll
    for (int kk = 0; kk < 32; ++kk) {
      float4 av = *(const float4*)&As[kk][ty << 2];
      float4 bv = *(const float4*)&Ws[kk][tx << 2];
      acc[0][0] = fmaf(av.x, bv.x, acc[0][0]);
      acc[0][1] = fmaf(av.x, bv.y, acc[0][1]);
      acc[0][2] = fmaf(av.x, bv.z, acc[0][2]);
      acc[0][3] = fmaf(av.x, bv.w, acc[0][3]);
      acc[1][0] = fmaf(av.y, bv.x, acc[1][0]);
      acc[1][1] = fmaf(av.y, bv.y, acc[1][1]);
      acc[1][2] = fmaf(av.y, bv.z, acc[1][2]);
      acc[1][3] = fmaf(av.y, bv.w, acc[1][3]);
      acc[2][0] = fmaf(av.z, bv.x, acc[2][0]);
      acc[2][1] = fmaf(av.z, bv.y, acc[2][1]);
      acc[2][2] = fmaf(av.z, bv.z, acc[2][2]);
      acc[2][3] = fmaf(av.z, bv.w, acc[2][3]);
      acc[3][0] = fmaf(av.w, bv.x, acc[3][0]);
      acc[3][1] = fmaf(av.w, bv.y, acc[3][1]);
      acc[3][2] = fmaf(av.w, bv.z, acc[3][2]);
      acc[3][3] = fmaf(av.w, bv.w, acc[3][3]);
    }
  }

  // BN(eval): y = ((h - mean) * (gamma * rsqrt(var+eps))) + beta
  const float* gma = bnp;
  const float* bta = bnp + 256;
  const float* mea = bnp + 512;
  const float* vra = bnp + 768;
  float sc[4], me[4], be[4];
#pragma unroll
  for (int jj = 0; jj < 4; ++jj) {
    int o = n0 + (tx << 2) + jj;
    sc[jj] = __fmul_rn(gma[o], 1.0f / sqrtf(__fadd_rn(vra[o], 1e-5f)));
    me[jj] = mea[o];
    be[jj] = bta[o];
  }
#pragma unroll
  for (int ii = 0; ii < 4; ++ii) {
    int row = m0 + (ty << 2) + ii;
    float4 y;
    y.x = __fadd_rn(__fmul_rn(__fsub_rn(acc[ii][0], me[0]), sc[0]), be[0]);
    y.y = __fadd_rn(__fmul_rn(__fsub_rn(acc[ii][1], me[1]), sc[1]), be[1]);
    y.z = __fadd_rn(__fmul_rn(__fsub_rn(acc[ii][2], me[2]), sc[2]), be[2]);
    y.w = __fadd_rn(__fmul_rn(__fsub_rn(acc[ii][3], me[3]), sc[3]), be[3]);
    *(float4*)(Out + (size_t)row * 256 + n0 + (tx << 2)) = y;
  }
}

// ---------------------------------------------------------------------------
// LIF over T (TAU=2, hard reset) + pack spikes into per-head 32-bit masks.
// Merged q/k/v: blockIdx.y selects the branch.
// ---------------------------------------------------------------------------
__global__ __launch_bounds__(256) void lif_pack3(
    const float* __restrict__ h0, const float* __restrict__ h1,
    const float* __restrict__ h2,
    u32* __restrict__ m0p, u32* __restrict__ m1p, u32* __restrict__ m2p)
{
  const float* h = (blockIdx.y == 0) ? h0 : (blockIdx.y == 1) ? h1 : h2;
  u32* mask      = (blockIdx.y == 0) ? m0p : (blockIdx.y == 1) ? m1p : m2p;
  const int blk = blockIdx.x;          // b*256 + n
  const int b = blk >> 8, n = blk & 255;
  const int c = threadIdx.x;
  const int wave = c >> 6, lane = c & 63;
  const size_t idx = ((size_t)b * 256 + n) * 256 + c;
  float v = 0.0f;
#pragma unroll
  for (int t = 0; t < 4; ++t) {
    float xv = h[idx + (size_t)t * BNC_];
    v = __fadd_rn(v, __fmul_rn(__fsub_rn(xv, v), 0.5f));
    bool s = (v >= 1.0f);
    u64 bal = __ballot(s);
    const int h0i = wave << 1;
    u32* mptr = mask + ((size_t)(t * 16 + b) * 8) * 256 + n;
    if (lane == 0)  mptr[(size_t)h0i * 256]       = (u32)bal;
    if (lane == 32) mptr[(size_t)(h0i + 1) * 256] = (u32)(bal >> 32);
    v = s ? 0.0f : v;
  }
}

// ---------------------------------------------------------------------------
// Fused attention: QK^T (popcount) + rel-bias + exact top-64 threshold + PV.
// Grid (512 tbh, 8 row-groups); 4 waves/block, wave handles 8 rows.
// Round-2 change: grid.y=8 split fixes 22% occupancy (was 2 blocks/CU).
// ---------------------------------------------------------------------------
__global__ __launch_bounds__(256) void attn_topk_pv(
    const u32* __restrict__ qmask, const u32* __restrict__ kmask,
    const u32* __restrict__ vmask, const float* __restrict__ table,
    float* __restrict__ outPV)
{
  __shared__ __align__(16) u32 kms[256];
  __shared__ __align__(16) u32 vms[256];
  __shared__ __align__(16) float bias[511];
  __shared__ __align__(16) float arow[4][256];

  const int tbh = blockIdx.x;
  const int rg = blockIdx.y;
  const int hh = tbh & 7;
  const int tid = threadIdx.x;

  kms[tid] = kmask[((size_t)tbh << 8) + tid];
  vms[tid] = vmask[((size_t)tbh << 8) + tid];
  bias[tid] = table[tid * 8 + hh];
  if (tid < 255) bias[256 + tid] = table[(256 + tid) * 8 + hh];
  __syncthreads();

  const int wave = tid >> 6, lane = tid & 63;
  const int d = lane & 31, half = lane >> 5;

#pragma unroll
  for (int it = 0; it < 8; ++it) {
    const int i = (rg << 5) + (it << 2) + wave;
    const u32 qm = qmask[((size_t)tbh << 8) + i];
    float a[4];
    u32 u[4];
#pragma unroll
    for (int r = 0; r < 4; ++r) {
      const int j = lane + (r << 6);
      const int m = __popc(qm & kms[j]);
      float av = __fmul_rn((float)m, 0.0625f);     // * C^-0.5 = 1/16 (exact)
      av = __fadd_rn(av, bias[j - i + 255]);        // one rounded add, == ref
      a[r] = av;
      const u32 bb = __float_as_uint(av);
      u[r] = bb ^ ((u32)((int)bb >> 31) | 0x80000000u);  // order-preserving map
    }
    // MSB-greedy search for the exact 64th-largest value (ties kept like ref)
    u32 t = 0u;
#pragma unroll
    for (int bit = 31; bit >= 0; --bit) {
      const u32 cand = t | (1u << bit);
      const int cnt = __popcll(__ballot(u[0] >= cand)) +
                      __popcll(__ballot(u[1] >= cand)) +
                      __popcll(__ballot(u[2] >= cand)) +
                      __popcll(__ballot(u[3] >= cand));
      if (cnt >= 64) t = cand;
    }
#pragma unroll
    for (int r = 0; r < 4; ++r)
      arow[wave][lane + (r << 6)] = (u[r] >= t) ? a[r] : 0.0f;
    // within-wave LDS RAW: DS ops are in-order per wave; waitcnt + clobber
    asm volatile("s_waitcnt lgkmcnt(0)" ::: "memory");

    // PV: lane (half,d) sums its half of j over v-spike bits (order == ref)
    float s = 0.0f;
#pragma unroll 8
    for (int jj = 0; jj < 32; ++jj) {
      const int j = (half << 7) + (jj << 2);
      float4 a4 = *(const float4*)&arow[wave][j];
      uint4 v4 = *(const uint4*)&vms[j];
      if ((v4.x >> d) & 1u) s += a4.x;
      if ((v4.y >> d) & 1u) s += a4.y;
      if ((v4.z >> d) & 1u) s += a4.z;
      if ((v4.w >> d) & 1u) s += a4.w;
    }
    s += __shfl_xor(s, 32, 64);
    if (half == 0)
      outPV[(((size_t)tbh << 8) + i) * 32 + d] = s;
  }
}

// ---------------------------------------------------------------------------
// attn_lif: LIF over T on PV output, with [T,B,H,N,D] -> [T,B,N,C] transpose.
// ---------------------------------------------------------------------------
__global__ __launch_bounds__(256) void attn_lif(
    const float* __restrict__ pv, float* __restrict__ sout)
{
  const int blk = blockIdx.x;          // b*256 + n
  const int b = blk >> 8, n = blk & 255;
  const int c = threadIdx.x;
  const int hh = c >> 5, d = c & 31;
  float v = 0.0f;
#pragma unroll
  for (int t = 0; t < 4; ++t) {
    float xv = pv[(((size_t)(t * 16 + b) * 8 + hh) << 13) + (n << 5) + d];
    v = __fadd_rn(v, __fmul_rn(__fsub_rn(xv, v), 0.5f));
    bool s = (v >= 1.0f);
    sout[(((size_t)(t * 16 + b) << 8) + n) * 256 + c] = s ? 1.0f : 0.0f;
    v = s ? 0.0f : v;
  }
}

// ---------------------------------------------------------------------------
// Final LIF: hproj [T,B,N,C] -> d_out spikes [T,B,N,C]
// ---------------------------------------------------------------------------
__global__ __launch_bounds__(256) void final_lif(
    const float* __restrict__ hp, float* __restrict__ out)
{
  const size_t base = (size_t)blockIdx.x * 256 + threadIdx.x;
  float v = 0.0f;
#pragma unroll
  for (int t = 0; t < 4; ++t) {
    float xv = hp[base + (size_t)t * BNC_];
    v = __fadd_rn(v, __fmul_rn(__fsub_rn(xv, v), 0.5f));
    bool s = (v >= 1.0f);
    out[base + (size_t)t * BNC_] = s ? 1.0f : 0.0f;
    v = s ? 0.0f : v;
  }
}

// ---------------------------------------------------------------------------
extern "C" void kernel_launch(void* const* d_in, const int* in_sizes, int n_in,
                              void* d_out, int out_size, void* d_ws, size_t ws_size,
                              hipStream_t stream) {
  const float* x       = (const float*)d_in[0];
  const float* wq      = (const float*)d_in[1];
  const float* wk      = (const float*)d_in[2];
  const float* wv      = (const float*)d_in[3];
  const float* bnq     = (const float*)d_in[4];
  const float* bnk     = (const float*)d_in[5];
  const float* bnv     = (const float*)d_in[6];
  const float* proj_w  = (const float*)d_in[7];
  const float* proj_bn = (const float*)d_in[8];
  const float* rtable  = (const float*)d_in[9];
  float* out = (float*)d_out;

  float* ws = (float*)d_ws;
  float* hq = ws;                  // NELEM floats
  float* hk = ws + (size_t)NELEM;
  float* hv = ws + (size_t)NELEM * 2;
  u32* mq = (u32*)(ws + (size_t)NELEM * 3);   // 131072 u32 each
  u32* mk = mq + 131072;
  u32* mv = mk + 131072;
  float* outPV = hq;   // reuse: hq dead after mask extraction
  float* sout  = hk;
  float* hproj = hv;

  dim3 ggrid(4, 256);
  gemm_bn<<<ggrid, 256, 0, stream>>>(x, wq, bnq, hq);
  gemm_bn<<<ggrid, 256, 0, stream>>>(x, wk, bnk, hk);
  gemm_bn<<<ggrid, 256, 0, stream>>>(x, wv, bnv, hv);

  lif_pack3<<<dim3(4096, 3), 256, 0, stream>>>(hq, hk, hv, mq, mk, mv);

  attn_topk_pv<<<dim3(512, 8), 256, 0, stream>>>(mq, mk, mv, rtable, outPV);

  attn_lif<<<4096, 256, 0, stream>>>(outPV, sout);

  gemm_bn<<<ggrid, 256, 0, stream>>>(sout, proj_w, proj_bn, hproj);

  final_lif<<<4096, 256, 0, stream>>>(hproj, out);
}

// Round 4
// 335.299 us; speedup vs baseline: 1.7258x; 1.1296x over previous
//
#include <hip/hip_runtime.h>

typedef unsigned int u32;
typedef unsigned long long u64;

// Problem constants
#define T_ 4
#define B_ 16
#define N_ 256
#define C_ 256
#define H_ 8
#define D_ 32
#define BNC_ 1048576   // B*N*C
#define NELEM 4194304  // T*B*N*C

// ---------------------------------------------------------------------------
// GEMM + eval-BatchNorm epilogue.  Out[m,o] = BN(sum_c A[m,c]*W[o,c])
// A:[16384,256] W:[256,256] row-major.
// 128x64 tile, 128 threads, 8x8 microtile (0.5 B/FLOP LDS ratio,
// was 1.0 at 4x4 -> LDS-pipe-bound). BK=32, k-major LDS, single buffer,
// register prefetch of next k-slab under the 2048-FMA compute phase.
// FMA chain per output stays strictly k-ascending (bit-exact vs reference).
// ---------------------------------------------------------------------------
__global__ __launch_bounds__(128) void gemm_bn(
    const float* __restrict__ A, const float* __restrict__ W,
    const float* __restrict__ bnp, float* __restrict__ Out)
{
  __shared__ float As[32][132];   // k-major; 132 floats = 528B (16B multiple)
  __shared__ float Ws[32][68];    // 272B stride (16B multiple)
  const int tid = threadIdx.x;
  const int m0 = blockIdx.y << 7;      // 128 rows
  const int n0 = blockIdx.x << 6;      // 64 cols
  const int tx = tid & 7;              // col group
  const int ty = tid >> 3;             // row group

  float acc[8][8] = {};
  float4 pa[8], pb[4];

#define LOADA(k0)                                                          \
  _Pragma("unroll") for (int c = 0; c < 8; ++c) {                          \
    int id2 = tid + (c << 7); int row = id2 >> 3; int k4 = (id2 & 7) << 2; \
    pa[c] = *(const float4*)(A + (size_t)(m0 + row) * 256 + (k0) + k4);    \
  }
#define LOADB(k0)                                                          \
  _Pragma("unroll") for (int c = 0; c < 4; ++c) {                          \
    int id2 = tid + (c << 7); int row = id2 >> 3; int k4 = (id2 & 7) << 2; \
    pb[c] = *(const float4*)(W + (size_t)(n0 + row) * 256 + (k0) + k4);    \
  }

  LOADA(0); LOADB(0);

  for (int s = 0; s < 8; ++s) {
#pragma unroll
    for (int c = 0; c < 8; ++c) {
      int id2 = tid + (c << 7); int row = id2 >> 3; int k4 = (id2 & 7) << 2;
      As[k4+0][row] = pa[c].x; As[k4+1][row] = pa[c].y;
      As[k4+2][row] = pa[c].z; As[k4+3][row] = pa[c].w;
    }
#pragma unroll
    for (int c = 0; c < 4; ++c) {
      int id2 = tid + (c << 7); int row = id2 >> 3; int k4 = (id2 & 7) << 2;
      Ws[k4+0][row] = pb[c].x; Ws[k4+1][row] = pb[c].y;
      Ws[k4+2][row] = pb[c].z; Ws[k4+3][row] = pb[c].w;
    }
    __syncthreads();
    if (s < 7) { int k0n = (s + 1) << 5; LOADA(k0n); LOADB(k0n); }
#pragma unroll
    for (int kk = 0; kk < 32; ++kk) {
      float4 a0 = *(const float4*)&As[kk][ty << 3];
      float4 a1 = *(const float4*)&As[kk][(ty << 3) + 4];
      float4 b0 = *(const float4*)&Ws[kk][tx << 3];
      float4 b1 = *(const float4*)&Ws[kk][(tx << 3) + 4];
      float av[8] = {a0.x,a0.y,a0.z,a0.w,a1.x,a1.y,a1.z,a1.w};
      float bv[8] = {b0.x,b0.y,b0.z,b0.w,b1.x,b1.y,b1.z,b1.w};
#pragma unroll
      for (int ii = 0; ii < 8; ++ii)
#pragma unroll
        for (int jj = 0; jj < 8; ++jj)
          acc[ii][jj] = fmaf(av[ii], bv[jj], acc[ii][jj]);
    }
    __syncthreads();
  }

  // BN(eval): identical op sequence to rounds 1-2 (passed absmax 0.0)
  const float* gma = bnp;
  const float* bta = bnp + 256;
  const float* mea = bnp + 512;
  const float* vra = bnp + 768;
  float sc[8], me[8], be[8];
#pragma unroll
  for (int jj = 0; jj < 8; ++jj) {
    int o = n0 + (tx << 3) + jj;
    sc[jj] = __fmul_rn(gma[o], 1.0f / sqrtf(__fadd_rn(vra[o], 1e-5f)));
    me[jj] = mea[o];
    be[jj] = bta[o];
  }
#pragma unroll
  for (int ii = 0; ii < 8; ++ii) {
    int row = m0 + (ty << 3) + ii;
    float4 y0, y1;
    y0.x = __fadd_rn(__fmul_rn(__fsub_rn(acc[ii][0], me[0]), sc[0]), be[0]);
    y0.y = __fadd_rn(__fmul_rn(__fsub_rn(acc[ii][1], me[1]), sc[1]), be[1]);
    y0.z = __fadd_rn(__fmul_rn(__fsub_rn(acc[ii][2], me[2]), sc[2]), be[2]);
    y0.w = __fadd_rn(__fmul_rn(__fsub_rn(acc[ii][3], me[3]), sc[3]), be[3]);
    y1.x = __fadd_rn(__fmul_rn(__fsub_rn(acc[ii][4], me[4]), sc[4]), be[4]);
    y1.y = __fadd_rn(__fmul_rn(__fsub_rn(acc[ii][5], me[5]), sc[5]), be[5]);
    y1.z = __fadd_rn(__fmul_rn(__fsub_rn(acc[ii][6], me[6]), sc[6]), be[6]);
    y1.w = __fadd_rn(__fmul_rn(__fsub_rn(acc[ii][7], me[7]), sc[7]), be[7]);
    *(float4*)(Out + (size_t)row * 256 + n0 + (tx << 3))     = y0;
    *(float4*)(Out + (size_t)row * 256 + n0 + (tx << 3) + 4) = y1;
  }
}

// ---------------------------------------------------------------------------
// LIF over T (TAU=2, hard reset) + pack spikes into per-head 32-bit masks.
// ---------------------------------------------------------------------------
__global__ __launch_bounds__(256) void lif_pack3(
    const float* __restrict__ h0, const float* __restrict__ h1,
    const float* __restrict__ h2,
    u32* __restrict__ m0p, u32* __restrict__ m1p, u32* __restrict__ m2p)
{
  const float* h = (blockIdx.y == 0) ? h0 : (blockIdx.y == 1) ? h1 : h2;
  u32* mask      = (blockIdx.y == 0) ? m0p : (blockIdx.y == 1) ? m1p : m2p;
  const int blk = blockIdx.x;          // b*256 + n
  const int b = blk >> 8, n = blk & 255;
  const int c = threadIdx.x;
  const int wave = c >> 6, lane = c & 63;
  const size_t idx = ((size_t)b * 256 + n) * 256 + c;
  float v = 0.0f;
#pragma unroll
  for (int t = 0; t < 4; ++t) {
    float xv = h[idx + (size_t)t * BNC_];
    v = __fadd_rn(v, __fmul_rn(__fsub_rn(xv, v), 0.5f));
    bool s = (v >= 1.0f);
    u64 bal = __ballot(s);
    const int h0i = wave << 1;
    u32* mptr = mask + ((size_t)(t * 16 + b) * 8) * 256 + n;
    if (lane == 0)  mptr[(size_t)h0i * 256]       = (u32)bal;
    if (lane == 32) mptr[(size_t)(h0i + 1) * 256] = (u32)(bal >> 32);
    v = s ? 0.0f : v;
  }
}

// ---------------------------------------------------------------------------
// Fused attention: QK^T (popcount) + rel-bias + exact top-64 + sparse PV.
// (a) early-exit top-k when cnt==64 (exact: the keep-SET is then identical
// to {u>=kth}); (b) compact kept (a, vms[j]) pairs into per-wave LDS
// preserving j-ascending order per half, then PV iterates only ~35
// entries/half (was 128 dense). Skipped terms added exactly +0.0 before
// (partial sums never -0.0 in RN), so dropping them is bit-exact.
// ---------------------------------------------------------------------------
__global__ __launch_bounds__(256) void attn_topk_pv(
    const u32* __restrict__ qmask, const u32* __restrict__ kmask,
    const u32* __restrict__ vmask, const float* __restrict__ table,
    float* __restrict__ outPV)
{
  __shared__ __align__(16) float bias[511];
  __shared__ __align__(16) u64 comp[4][2][132];  // [wave][half][entries]

  const int tbh = blockIdx.x;
  const int rg = blockIdx.y;
  const int hh = tbh & 7;
  const int tid = threadIdx.x;

  bias[tid] = table[tid * 8 + hh];
  if (tid < 255) bias[256 + tid] = table[(256 + tid) * 8 + hh];
  __syncthreads();

  const int wave = tid >> 6, lane = tid & 63;
  const int d = lane & 31, half = lane >> 5;

  // row-invariant per-lane K/V mask words (j = lane + 64r)
  u32 kmr[4], vmr[4];
#pragma unroll
  for (int r = 0; r < 4; ++r) {
    kmr[r] = kmask[((size_t)tbh << 8) + lane + (r << 6)];
    vmr[r] = vmask[((size_t)tbh << 8) + lane + (r << 6)];
  }
  const u64 below = (1ull << lane) - 1ull;
  u64* const clo = &comp[wave][0][0];
  u64* const chi = &comp[wave][1][0];

#pragma unroll 1
  for (int it = 0; it < 8; ++it) {
    const int i = (rg << 5) + (it << 2) + wave;
    const u32 qm = qmask[((size_t)tbh << 8) + i];
    float a[4]; u32 u[4];
#pragma unroll
    for (int r = 0; r < 4; ++r) {
      const int j = lane + (r << 6);
      const int m = __popc(qm & kmr[r]);
      float av = __fmul_rn((float)m, 0.0625f);     // * C^-0.5 = 1/16 exact
      av = __fadd_rn(av, bias[j - i + 255]);        // one rounded add == ref
      a[r] = av;
      const u32 bb = __float_as_uint(av);
      u[r] = bb ^ ((u32)((int)bb >> 31) | 0x80000000u);
    }
    // MSB-greedy exact 64th-largest; early exit when keep-set pinned
    u32 t = 0u;
    for (int bit = 31; bit >= 0; --bit) {
      const u32 cand = t | (1u << bit);
      const int cnt = __popcll(__ballot(u[0] >= cand)) +
                      __popcll(__ballot(u[1] >= cand)) +
                      __popcll(__ballot(u[2] >= cand)) +
                      __popcll(__ballot(u[3] >= cand));
      if (cnt >= 64) { t = cand; if (cnt == 64) break; }
    }
    // keep ballots -> compaction positions (j-ascending per half:
    // lo half = [B0 lanes asc, B1 lanes asc], hi = [B2, B3])
    const u64 B0 = __ballot(u[0] >= t), B1 = __ballot(u[1] >= t);
    const u64 B2 = __ballot(u[2] >= t), B3 = __ballot(u[3] >= t);
    const int c0 = __popcll(B0), c1 = __popcll(B1);
    const int c2 = __popcll(B2), c3 = __popcll(B3);
    const int p0 = __popcll(B0 & below);
    const int p1 = c0 + __popcll(B1 & below);
    const int p2 = __popcll(B2 & below);
    const int p3 = c2 + __popcll(B3 & below);
    if (u[0] >= t) clo[p0] = ((u64)vmr[0] << 32) | (u64)__float_as_uint(a[0]);
    if (u[1] >= t) clo[p1] = ((u64)vmr[1] << 32) | (u64)__float_as_uint(a[1]);
    if (u[2] >= t) chi[p2] = ((u64)vmr[2] << 32) | (u64)__float_as_uint(a[2]);
    if (u[3] >= t) chi[p3] = ((u64)vmr[3] << 32) | (u64)__float_as_uint(a[3]);
    const int nlo = c0 + c1, nhi = c2 + c3;
    if (lane < 2)      clo[nlo + lane] = 0ull;        // zero pads (odd tail)
    else if (lane < 4) chi[nhi + lane - 2] = 0ull;
    asm volatile("s_waitcnt lgkmcnt(0)" ::: "memory");

    // sparse PV: lane (half,d) walks its half's compact list, j-ascending
    const int n = half ? nhi : nlo;
    const u64* cp = half ? chi : clo;
    const int gn = (n + 1) >> 1;
    float s = 0.0f;
    for (int g = 0; g < gn; ++g) {
      uint4 e = *(const uint4*)(cp + ((size_t)g << 1));  // (a0,vm0,a1,vm1)
      const u32 mk0 = (u32)__builtin_amdgcn_sbfe((int)e.y, d, 1);
      s = __fadd_rn(s, __uint_as_float(e.x & mk0));
      const u32 mk1 = (u32)__builtin_amdgcn_sbfe((int)e.w, d, 1);
      s = __fadd_rn(s, __uint_as_float(e.z & mk1));
    }
    s += __shfl_xor(s, 32, 64);     // half0: s_lo + s_hi (ref order)
    if (half == 0)
      outPV[(((size_t)tbh << 8) + i) * 32 + d] = s;
  }
}

// ---------------------------------------------------------------------------
// attn_lif: LIF over T on PV output, [T,B,H,N,D] -> [T,B,N,C] transpose.
// ---------------------------------------------------------------------------
__global__ __launch_bounds__(256) void attn_lif(
    const float* __restrict__ pv, float* __restrict__ sout)
{
  const int blk = blockIdx.x;          // b*256 + n
  const int b = blk >> 8, n = blk & 255;
  const int c = threadIdx.x;
  const int hh = c >> 5, d = c & 31;
  float v = 0.0f;
#pragma unroll
  for (int t = 0; t < 4; ++t) {
    float xv = pv[(((size_t)(t * 16 + b) * 8 + hh) << 13) + (n << 5) + d];
    v = __fadd_rn(v, __fmul_rn(__fsub_rn(xv, v), 0.5f));
    bool s = (v >= 1.0f);
    sout[(((size_t)(t * 16 + b) << 8) + n) * 256 + c] = s ? 1.0f : 0.0f;
    v = s ? 0.0f : v;
  }
}

// ---------------------------------------------------------------------------
// Final LIF: hproj [T,B,N,C] -> d_out spikes [T,B,N,C]
// ---------------------------------------------------------------------------
__global__ __launch_bounds__(256) void final_lif(
    const float* __restrict__ hp, float* __restrict__ out)
{
  const size_t base = (size_t)blockIdx.x * 256 + threadIdx.x;
  float v = 0.0f;
#pragma unroll
  for (int t = 0; t < 4; ++t) {
    float xv = hp[base + (size_t)t * BNC_];
    v = __fadd_rn(v, __fmul_rn(__fsub_rn(xv, v), 0.5f));
    bool s = (v >= 1.0f);
    out[base + (size_t)t * BNC_] = s ? 1.0f : 0.0f;
    v = s ? 0.0f : v;
  }
}

// ---------------------------------------------------------------------------
extern "C" void kernel_launch(void* const* d_in, const int* in_sizes, int n_in,
                              void* d_out, int out_size, void* d_ws, size_t ws_size,
                              hipStream_t stream) {
  const float* x       = (const float*)d_in[0];
  const float* wq      = (const float*)d_in[1];
  const float* wk      = (const float*)d_in[2];
  const float* wv      = (const float*)d_in[3];
  const float* bnq     = (const float*)d_in[4];
  const float* bnk     = (const float*)d_in[5];
  const float* bnv     = (const float*)d_in[6];
  const float* proj_w  = (const float*)d_in[7];
  const float* proj_bn = (const float*)d_in[8];
  const float* rtable  = (const float*)d_in[9];
  float* out = (float*)d_out;

  float* ws = (float*)d_ws;
  float* hq = ws;                  // NELEM floats
  float* hk = ws + (size_t)NELEM;
  float* hv = ws + (size_t)NELEM * 2;
  u32* mq = (u32*)(ws + (size_t)NELEM * 3);   // 131072 u32 each
  u32* mk = mq + 131072;
  u32* mv = mk + 131072;
  float* outPV = hq;   // reuse: hq dead after mask extraction
  float* sout  = hk;
  float* hproj = hv;

  dim3 ggrid(4, 128);   // (N/64, M/128)
  gemm_bn<<<ggrid, 128, 0, stream>>>(x, wq, bnq, hq);
  gemm_bn<<<ggrid, 128, 0, stream>>>(x, wk, bnk, hk);
  gemm_bn<<<ggrid, 128, 0, stream>>>(x, wv, bnv, hv);

  lif_pack3<<<dim3(4096, 3), 256, 0, stream>>>(hq, hk, hv, mq, mk, mv);

  attn_topk_pv<<<dim3(512, 8), 256, 0, stream>>>(mq, mk, mv, rtable, outPV);

  attn_lif<<<4096, 256, 0, stream>>>(outPV, sout);

  gemm_bn<<<ggrid, 128, 0, stream>>>(sout, proj_w, proj_bn, hproj);

  final_lif<<<4096, 256, 0, stream>>>(hproj, out);
}